// Round 3
// baseline (14990.846 us; speedup 1.0000x reference)
//
#include <hip/hip_runtime.h>

typedef unsigned short u16;
typedef __attribute__((ext_vector_type(8))) unsigned short ushort8;
typedef __attribute__((ext_vector_type(4))) float f32x4;
typedef __attribute__((ext_vector_type(8))) __bf16 bf16x8;

#define N_B 256
#define LSEQ 128
#define AROW 2304   // 768 (h1) + 2*768 (h2 double-buffer phases)
#define NBLK 256

#define MFMA_B16(a, b, c) __builtin_amdgcn_mfma_f32_16x16x32_bf16( \
    __builtin_bit_cast(bf16x8, a), __builtin_bit_cast(bf16x8, b), c, 0, 0, 0)

#define GLLDS(gp, lp) __builtin_amdgcn_global_load_lds( \
    (const __attribute__((address_space(1))) void*)(gp), \
    (__attribute__((address_space(3))) void*)(lp), 16, 0, 0)

// ---- workspace layout (byte offsets) ----
#define OFF_BP2   0ull
#define SZ_BP2    (48ull*192*512*2)
#define OFF_BP1   (OFF_BP2 + SZ_BP2)
#define SZ_BP1    (24ull*192*512*2)
#define OFF_W1P   (OFF_BP1 + SZ_BP1)
#define SZ_W1P    (24ull*32*512*2)
#define OFF_WIH1T (OFF_W1P + SZ_W1P)
#define SZ_WIH1T  (9ull*3072*4)
#define OFF_BS1   (OFF_WIH1T + SZ_WIH1T)
#define OFF_BS2   (OFF_BS1 + 3072*4)
#define OFF_G1P   (OFF_BS2 + 3072*4)
#define SZ_G1P    (256ull*3072*4)
#define OFF_PBUF  (OFF_G1P + SZ_G1P)
#define SZ_PBUF   (256ull*8*4)
#define OFF_ZERO  (OFF_PBUF + SZ_PBUF)
#define OFF_ACAT  OFF_ZERO
#define SZ_ACAT   (256ull*2304*2)
#define OFF_C1    (OFF_ACAT + SZ_ACAT)
#define OFF_C2    (OFF_C1 + 256ull*768*4)
#define OFF_SB    (OFF_C2 + 256ull*768*4)
#define OFF_BAR   (OFF_SB + 1024)          // [0]=cnt  [16]=gen (separate lines)
#define OFF_END   (OFF_BAR + 128)
#define ZERO_BYTES (OFF_END - OFF_ZERO)

__device__ __forceinline__ float sigf(float v) { return 1.f / (1.f + __expf(-v)); }
__device__ __forceinline__ float tanhfast(float v) { return 1.f - 2.f / (__expf(2.f * v) + 1.f); }
__device__ __forceinline__ u16 f2bf(float f) {
  union { float f; unsigned u; } v; v.f = f;
  unsigned r = v.u + 0x7fffu + ((v.u >> 16) & 1u);   // round-to-nearest-even
  return (u16)(r >> 16);
}

struct Params {
  const float* x;
  const u16* Bp2; const u16* Bp1; const u16* W1p;
  const float* Wih1t; const float* bs1; const float* bs2;
  const float* b1; const float* W2; const float* b2;
  u16* Acat; float* g1p; float* c1; float* c2; float* sb; float* pbuf;
  unsigned* bar;
  float* outs; float* stores;
};

// ---------------------------------------------------------------------------
// Device-scope grid barrier (sense-free: monotone generation counter).
// Safe under plain launch: grid(256 blk, 50KB LDS) always fully co-resident
// on 256 CUs (>=1 blk/CU at any VGPR count). Atomics at AGENT scope hit the
// coherence point (per-XCD L2s are not cross-coherent).
// ---------------------------------------------------------------------------
__device__ __forceinline__ void gbar(unsigned* cnt, unsigned* gen, unsigned& lg) {
  __syncthreads();
  if (threadIdx.x == 0) {
    unsigned g = lg;
    unsigned prev = __hip_atomic_fetch_add(cnt, 1u, __ATOMIC_ACQ_REL, __HIP_MEMORY_SCOPE_AGENT);
    if (prev == NBLK - 1u) {
      __hip_atomic_store(cnt, 0u, __ATOMIC_RELAXED, __HIP_MEMORY_SCOPE_AGENT);
      __hip_atomic_fetch_add(gen, 1u, __ATOMIC_ACQ_REL, __HIP_MEMORY_SCOPE_AGENT);
    } else {
      while (__hip_atomic_load(gen, __ATOMIC_ACQUIRE, __HIP_MEMORY_SCOPE_AGENT) == g)
        __builtin_amdgcn_s_sleep(1);
    }
    lg = g + 1;
  }
  __syncthreads();
}

// ---------------------------------------------------------------------------
// One-time packing: weights -> bf16 MFMA fragment layout (round-1 verified).
// B fragment (kt, jt): lane l, elem e holds B[kt*32 + (l>>4)*8 + e][jt*16 + (l&15)].
// ---------------------------------------------------------------------------
__global__ void pack_kernel(const float* __restrict__ Wih1, const float* __restrict__ bih1,
                            const float* __restrict__ Whh1, const float* __restrict__ bhh1,
                            const float* __restrict__ Wih2, const float* __restrict__ bih2,
                            const float* __restrict__ Whh2, const float* __restrict__ bhh2,
                            const float* __restrict__ W1,
                            u16* __restrict__ Bp2, u16* __restrict__ Bp1, u16* __restrict__ W1p,
                            float* __restrict__ Wih1t, float* __restrict__ bs1, float* __restrict__ bs2) {
  const long NB2 = 48l * 192 * 512, NB1 = 24l * 192 * 512, NW1 = 24l * 32 * 512, NT = 9l * 3072;
  const long total = NB2 + NB1 + NW1 + NT + 3072 * 2;
  for (long idx = (long)blockIdx.x * 256 + threadIdx.x; idx < total; idx += (long)gridDim.x * 256) {
    if (idx < NB2) {                       // Wcat2 = [W_ih2 ; W_hh2] (K=1536)
      long kt = idx / (192 * 512); long r = idx % (192 * 512);
      int jt = (int)(r / 512); int s = (int)(r % 512);
      int ll = s >> 3, e = s & 7;
      int k = (int)kt * 32 + ((ll >> 4) * 8) + e;
      int j = jt * 16 + (ll & 15);
      float v = (k < 768) ? Wih2[j * 768 + k] : Whh2[j * 768 + k - 768];
      Bp2[idx] = f2bf(v);
    } else if (idx < NB2 + NB1) {          // W_hh1 (K=768)
      long i = idx - NB2;
      long kt = i / (192 * 512); long r = i % (192 * 512);
      int jt = (int)(r / 512); int s = (int)(r % 512);
      int ll = s >> 3, e = s & 7;
      int k = (int)kt * 32 + ((ll >> 4) * 8) + e;
      int j = jt * 16 + (ll & 15);
      Bp1[i] = f2bf(Whh1[j * 768 + k]);
    } else if (idx < NB2 + NB1 + NW1) {    // W1 (K=768, N=512)
      long i = idx - NB2 - NB1;
      long kt = i / (32 * 512); long r = i % (32 * 512);
      int jt = (int)(r / 512); int s = (int)(r % 512);
      int ll = s >> 3, e = s & 7;
      int k = (int)kt * 32 + ((ll >> 4) * 8) + e;
      int j = jt * 16 + (ll & 15);
      W1p[i] = f2bf(W1[j * 768 + k]);
    } else if (idx < NB2 + NB1 + NW1 + NT) {  // W_ih1 transposed (fp32)
      long i = idx - NB2 - NB1 - NW1;
      int k = (int)(i / 3072), j = (int)(i % 3072);
      Wih1t[i] = Wih1[j * 9 + k];
    } else {
      long i = idx - NB2 - NB1 - NW1 - NT;
      if (i < 3072) bs1[i] = bih1[i] + bhh1[i];
      else { long j = i - 3072; bs2[j] = bih2[j] + bhh2[j]; }
    }
  }
}

// ---------------------------------------------------------------------------
// phase H: out-reduction, exact fp32 store integration, h1(t+1) activation.
// 64 blocks x 4 rows. t == -1 bootstraps (no FC; x/bias terms added inline).
// ---------------------------------------------------------------------------
__device__ __forceinline__ void phase_H(const Params& P, int t, int tid, int bid,
                                        float (*xsb)[8]) {
  const int n0 = bid * 4;
  if (tid < 4) {
    int n = n0 + tid;
    float ov = 0.f;
    if (t >= 0) {
      const float* pb = P.pbuf + n * 8;
      ov = ((pb[0] + pb[1]) + (pb[2] + pb[3])) + ((pb[4] + pb[5]) + (pb[6] + pb[7])) + P.b2[0];
      P.outs[n * LSEQ + t] = ov;
    }
    if (t < 127) {
      float cs = P.sb[n] + P.x[(n * LSEQ + t + 1) * 8] - ov;   // exact fp32 integration
      P.sb[n] = cs;
      P.stores[n * LSEQ + t + 1] = cs;
      xsb[0][4 + tid] = cs;
    }
  }
  if (t == -1 && tid < 32)
    xsb[1 + (tid >> 3)][tid & 7] = P.x[((n0 + (tid >> 3)) * LSEQ) * 8 + (tid & 7)];
  __syncthreads();
  if (t >= 127) return;
  for (int p = tid; p < 3072; p += 256) {
    int r = p / 768, m = p - r * 768;
    int n = n0 + r;
    float cs = xsb[0][4 + r];
    float g[4];
#pragma unroll
    for (int q = 0; q < 4; ++q) {
      int j = m + q * 768;
      float base;
      if (t >= 0) base = P.g1p[n * 3072 + j];
      else {
        base = P.bs1[j];
#pragma unroll
        for (int k = 0; k < 8; ++k) base += xsb[1 + r][k] * P.Wih1t[k * 3072 + j];
      }
      g[q] = base + cs * P.Wih1t[8 * 3072 + j];
    }
    float co = P.c1[n * 768 + m];
    float cn = sigf(g[1]) * co + sigf(g[0]) * tanhfast(g[2]);
    float h = sigf(g[3]) * tanhfast(cn);
    P.c1[n * 768 + m] = cn;
    P.Acat[n * AROW + m] = f2bf(h);
  }
}

// ---------------------------------------------------------------------------
// Persistent kernel (plain launch, own grid barrier): 3 syncs per timestep.
//   phase A: gates2 GEMM+h2 act (blocks 0..191) || g1p GEMM+x fixup (192..255)
//   phase F: FC1+ReLU+W2 partials, 128 blocks (16 rows x 64 cols)
//   phase H: out/store/h1, 64 blocks x 4 rows
// ---------------------------------------------------------------------------
__global__ __launch_bounds__(256) void lstm_fused(Params P) {
  __shared__ ushort8 sbuf[32 * 64];     // 32 KB: double-buffered staging (2 x 16 frags)
  __shared__ float fbuf[4][64][16];     // 16 KB: gates2 quadrant exchange / F reduction
  __shared__ float xsb[64][8];          // 2 KB: x rows (g1p fixup) / cs + bootstrap x (H)
  const int tid = threadIdx.x, l = tid & 63, w = tid >> 6;
  const int bid = blockIdx.x;
  unsigned* bcnt = P.bar;
  unsigned* bgen = P.bar + 16;
  unsigned lg = 0;

  if (bid < 64) phase_H(P, -1, tid, bid, xsb);
  gbar(bcnt, bgen, lg);

  for (int t = 0; t < 128; ++t) {
    // ================= phase A =================
    if (bid < 192) {
      // ---- gates2: 64 rows x (4 quadrants x 16 cols), K=1536 ----
      const int mg = bid % 48, rowbase = (bid / 48) * 64;
      const int rdbase = 768 + (t & 1) * 768;        // h2(t-1)
      const int wrbase = 768 + ((t + 1) & 1) * 768;  // h2(t)
      auto stage_g2 = [&](int kc, int half) {
#pragma unroll
        for (int i = 0; i < 4; ++i) {
          int f = w * 4 + i;                         // wave-uniform fragment id
          const u16* gp;
          if (f < 8) {                               // A: 4 row-tiles x 2 k-tiles
            int kt2 = f >> 2, rt = f & 3, kt = kc * 2 + kt2;
            int col = (kt >= 24) ? (rdbase + (kt - 24) * 32 + ((l >> 4) * 8))
                                 : (kt * 32 + ((l >> 4) * 8));
            gp = P.Acat + (rowbase + rt * 16 + (l & 15)) * AROW + col;
          } else {                                   // B: 4 quadrants x 2 k-tiles
            int g = f - 8, kt2 = g >> 2, q = g & 3, kt = kc * 2 + kt2;
            gp = P.Bp2 + (((long)(kt * 192 + q * 48 + mg)) << 9) + l * 8;
          }
          GLLDS(gp, &sbuf[(half * 16 + f) * 64]);
        }
      };
      f32x4 acc[4] = {};
      stage_g2(0, 0);
      for (int kc = 0; kc < 24; ++kc) {
        if (kc < 23) {
          stage_g2(kc + 1, (kc + 1) & 1);
          asm volatile("s_waitcnt vmcnt(4)" ::: "memory");
        } else {
          asm volatile("s_waitcnt vmcnt(0)" ::: "memory");
        }
        __builtin_amdgcn_s_barrier();
        __builtin_amdgcn_sched_barrier(0);
        const int base = (kc & 1) * 16;
#pragma unroll
        for (int kt2 = 0; kt2 < 2; ++kt2) {
          ushort8 bfr = sbuf[(base + 8 + kt2 * 4 + w) * 64 + l];
#pragma unroll
          for (int rt = 0; rt < 4; ++rt) {
            ushort8 a = sbuf[(base + kt2 * 4 + rt) * 64 + l];
            acc[rt] = MFMA_B16(a, bfr, acc[rt]);
          }
        }
        __builtin_amdgcn_sched_barrier(0);
        __builtin_amdgcn_s_barrier();
      }
      // epilogue: quadrant exchange -> h2/c2 update
#pragma unroll
      for (int rt = 0; rt < 4; ++rt)
#pragma unroll
        for (int reg = 0; reg < 4; ++reg) {
          int rl = rt * 16 + (l >> 4) * 4 + reg;
          fbuf[w][rl][l & 15] = acc[rt][reg] + P.bs2[w * 768 + mg * 16 + (l & 15)];
        }
      __syncthreads();
      for (int p = tid; p < 1024; p += 256) {
        int r = p >> 4, m = p & 15;
        float gi = fbuf[0][r][m], gf = fbuf[1][r][m], gg = fbuf[2][r][m], go = fbuf[3][r][m];
        int n = rowbase + r, mG = mg * 16 + m;
        float co = P.c2[n * 768 + mG];
        float cn = sigf(gf) * co + sigf(gi) * tanhfast(gg);
        float h = sigf(go) * tanhfast(cn);
        P.c2[n * 768 + mG] = cn;
        P.Acat[n * AROW + wrbase + mG] = f2bf(h);
      }
    } else {
      // ---- g1p: 64 rows x 192 cols, K=768; epilogue folds bias + x-projection ----
      const int b = bid - 192, rowbase = (b >> 4) * 64, jb = b & 15;
      if (t < 127) {
        for (int p = tid; p < 512; p += 256)
          xsb[p >> 3][p & 7] = P.x[((rowbase + (p >> 3)) * LSEQ + t + 1) * 8 + (p & 7)];
      } else {
        for (int p = tid; p < 512; p += 256) xsb[p >> 3][p & 7] = 0.f;
      }
      __syncthreads();
      auto stage_g1 = [&](int kt, int half) {
#pragma unroll
        for (int i = 0; i < 4; ++i) {
          int f = w * 4 + i;
          const u16* gp;
          if (f < 4) {                               // A: 4 row-tiles (h1 cols)
            gp = P.Acat + (rowbase + f * 16 + (l & 15)) * AROW + kt * 32 + ((l >> 4) * 8);
          } else {                                   // B: 12 j-tiles
            int jt_l = f - 4;
            gp = P.Bp1 + (((long)(kt * 192 + jb * 12 + jt_l)) << 9) + l * 8;
          }
          GLLDS(gp, &sbuf[(half * 16 + f) * 64]);
        }
      };
      f32x4 acc[3][4] = {};
      stage_g1(0, 0);
      for (int kt = 0; kt < 24; ++kt) {
        if (kt < 23) {
          stage_g1(kt + 1, (kt + 1) & 1);
          asm volatile("s_waitcnt vmcnt(4)" ::: "memory");
        } else {
          asm volatile("s_waitcnt vmcnt(0)" ::: "memory");
        }
        __builtin_amdgcn_s_barrier();
        __builtin_amdgcn_sched_barrier(0);
        const int base = (kt & 1) * 16;
        ushort8 a_[4];
#pragma unroll
        for (int rt = 0; rt < 4; ++rt) a_[rt] = sbuf[(base + rt) * 64 + l];
#pragma unroll
        for (int jj = 0; jj < 3; ++jj) {
          ushort8 bfr = sbuf[(base + 4 + w * 3 + jj) * 64 + l];
#pragma unroll
          for (int rt = 0; rt < 4; ++rt)
            acc[jj][rt] = MFMA_B16(a_[rt], bfr, acc[jj][rt]);
        }
        __builtin_amdgcn_sched_barrier(0);
        __builtin_amdgcn_s_barrier();
      }
      // epilogue: g1p = acc + bs1 + x(t+1) . W_ih1[:,0:8]   (cs term added in phase H)
      float wc[3][8], bsv[3];
#pragma unroll
      for (int jj = 0; jj < 3; ++jj) {
        int col = (jb * 12 + w * 3 + jj) * 16 + (l & 15);
        bsv[jj] = P.bs1[col];
#pragma unroll
        for (int k = 0; k < 8; ++k) wc[jj][k] = P.Wih1t[k * 3072 + col];
      }
#pragma unroll
      for (int rt = 0; rt < 4; ++rt)
#pragma unroll
        for (int reg = 0; reg < 4; ++reg) {
          int rl = rt * 16 + (l >> 4) * 4 + reg;
          int n = rowbase + rl;
          float xv[8];
#pragma unroll
          for (int k = 0; k < 8; ++k) xv[k] = xsb[rl][k];
#pragma unroll
          for (int jj = 0; jj < 3; ++jj) {
            float v = acc[jj][rt][reg] + bsv[jj];
#pragma unroll
            for (int k = 0; k < 8; ++k) v += xv[k] * wc[jj][k];
            P.g1p[n * 3072 + (jb * 12 + w * 3 + jj) * 16 + (l & 15)] = v;
          }
        }
    }
    gbar(bcnt, bgen, lg);

    // ========== phase F: FC partials (128 blocks: 16 rows x 64 cols) ==========
    if (bid < 128) {
      const int n0f = (bid >> 3) * 16, cg2 = bid & 7, ctg = cg2 * 4 + w;
      const int h2rd = 768 + ((t + 1) & 1) * 768;
      const u16* abase = P.Acat + (n0f + (l & 15)) * AROW + h2rd + ((l >> 4) * 8);
      const u16* bbase = P.W1p + ((long)ctg << 9) + l * 8;
      f32x4 facc = {};
#pragma unroll 6
      for (int kt = 0; kt < 24; ++kt) {
        ushort8 a = *reinterpret_cast<const ushort8*>(abase + kt * 32);
        ushort8 bf8 = *reinterpret_cast<const ushort8*>(bbase + kt * 16384);
        facc = MFMA_B16(a, bf8, facc);
      }
      int col = ctg * 16 + (l & 15);
      float w2v = P.W2[col], b1v = P.b1[col];
      float pr[4];
#pragma unroll
      for (int reg = 0; reg < 4; ++reg) pr[reg] = fmaxf(facc[reg] + b1v, 0.f) * w2v;
#pragma unroll
      for (int mm = 1; mm < 16; mm <<= 1)
#pragma unroll
        for (int reg = 0; reg < 4; ++reg) pr[reg] += __shfl_xor(pr[reg], mm);
      if ((l & 15) == 0)
#pragma unroll
        for (int reg = 0; reg < 4; ++reg) fbuf[w][(l >> 4) * 4 + reg][0] = pr[reg];
      __syncthreads();
      if (tid < 16)
        P.pbuf[(n0f + tid) * 8 + cg2] =
            fbuf[0][tid][0] + fbuf[1][tid][0] + fbuf[2][tid][0] + fbuf[3][tid][0];
    }
    gbar(bcnt, bgen, lg);

    // ================= phase H =================
    if (bid < 64) phase_H(P, t, tid, bid, xsb);
    gbar(bcnt, bgen, lg);
  }
}

extern "C" void kernel_launch(void* const* d_in, const int* in_sizes, int n_in,
                              void* d_out, int out_size, void* d_ws, size_t ws_size,
                              hipStream_t stream) {
  const float* x    = (const float*)d_in[0];
  const float* Wih1 = (const float*)d_in[1];
  const float* bih1 = (const float*)d_in[2];
  const float* Whh1 = (const float*)d_in[3];
  const float* bhh1 = (const float*)d_in[4];
  const float* Wih2 = (const float*)d_in[5];
  const float* bih2 = (const float*)d_in[6];
  const float* Whh2 = (const float*)d_in[7];
  const float* bhh2 = (const float*)d_in[8];
  const float* W1   = (const float*)d_in[9];
  const float* b1   = (const float*)d_in[10];
  const float* W2   = (const float*)d_in[11];
  const float* b2   = (const float*)d_in[12];

  char* ws = (char*)d_ws;
  u16* Bp2 = (u16*)(ws + OFF_BP2);
  u16* Bp1 = (u16*)(ws + OFF_BP1);
  u16* W1p = (u16*)(ws + OFF_W1P);
  float* Wih1t = (float*)(ws + OFF_WIH1T);
  float* bs1 = (float*)(ws + OFF_BS1);
  float* bs2 = (float*)(ws + OFF_BS2);
  float* g1p = (float*)(ws + OFF_G1P);
  float* pbuf = (float*)(ws + OFF_PBUF);
  u16* Acat = (u16*)(ws + OFF_ACAT);
  float* c1 = (float*)(ws + OFF_C1);
  float* c2 = (float*)(ws + OFF_C2);
  float* sb = (float*)(ws + OFF_SB);
  unsigned* bar = (unsigned*)(ws + OFF_BAR);
  float* outs = (float*)d_out;
  float* stores = outs + N_B * LSEQ;

  pack_kernel<<<2048, 256, 0, stream>>>(Wih1, bih1, Whh1, bhh1, Wih2, bih2, Whh2, bhh2, W1,
                                        Bp2, Bp1, W1p, Wih1t, bs1, bs2);
  hipMemsetAsync(ws + OFF_ZERO, 0, ZERO_BYTES, stream);

  Params Pr = {x, Bp2, Bp1, W1p, Wih1t, bs1, bs2, b1, W2, b2,
               Acat, g1p, c1, c2, sb, pbuf, bar, outs, stores};
  lstm_fused<<<NBLK, 256, 0, stream>>>(Pr);
}

// Round 4
// 14623.694 us; speedup vs baseline: 1.0251x; 1.0251x over previous
//
#include <hip/hip_runtime.h>

typedef unsigned short u16;
typedef __attribute__((ext_vector_type(8))) unsigned short ushort8;
typedef __attribute__((ext_vector_type(4))) float f32x4;
typedef __attribute__((ext_vector_type(8))) __bf16 bf16x8;

#define N_B 256
#define LSEQ 128
#define AROW 2304   // 768 (h1) + 2*768 (h2 double-buffer phases)
#define NBLK 256

#define MFMA_B16(a, b, c) __builtin_amdgcn_mfma_f32_16x16x32_bf16( \
    __builtin_bit_cast(bf16x8, a), __builtin_bit_cast(bf16x8, b), c, 0, 0, 0)

#define GLLDS(gp, lp) __builtin_amdgcn_global_load_lds( \
    (const __attribute__((address_space(1))) void*)(gp), \
    (__attribute__((address_space(3))) void*)(lp), 16, 0, 0)

// ---- workspace layout (byte offsets) ----
#define OFF_BP2   0ull
#define SZ_BP2    (48ull*192*512*2)
#define OFF_BP1   (OFF_BP2 + SZ_BP2)
#define SZ_BP1    (24ull*192*512*2)
#define OFF_W1P   (OFF_BP1 + SZ_BP1)
#define SZ_W1P    (24ull*32*512*2)
#define OFF_WIH1T (OFF_W1P + SZ_W1P)
#define SZ_WIH1T  (9ull*3072*4)
#define OFF_BS1   (OFF_WIH1T + SZ_WIH1T)
#define OFF_BS2   (OFF_BS1 + 3072*4)
#define OFF_G1P   (OFF_BS2 + 3072*4)
#define SZ_G1P    (256ull*3072*4)
#define OFF_PBUF  (OFF_G1P + SZ_G1P)
#define SZ_PBUF   (256ull*8*4)
#define OFF_ZERO  (OFF_PBUF + SZ_PBUF)
#define OFF_ACAT  OFF_ZERO
#define SZ_ACAT   (256ull*2304*2)
#define OFF_C1    (OFF_ACAT + SZ_ACAT)
#define OFF_C2    (OFF_C1 + 256ull*768*4)
#define OFF_SB    (OFF_C2 + 256ull*768*4)
#define OFF_BAR   (OFF_SB + 1024)      // bar[16]=gen; flags at bar+32 (256 x 32 uints)
#define SZ_BAR    (128 + 256*32*4)
#define OFF_END   (OFF_BAR + SZ_BAR)
#define ZERO_BYTES (OFF_END - OFF_ZERO)

__device__ __forceinline__ float sigf(float v) { return 1.f / (1.f + __expf(-v)); }
__device__ __forceinline__ float tanhfast(float v) { return 1.f - 2.f / (__expf(2.f * v) + 1.f); }
__device__ __forceinline__ u16 f2bf(float f) {
  union { float f; unsigned u; } v; v.f = f;
  unsigned r = v.u + 0x7fffu + ((v.u >> 16) & 1u);   // round-to-nearest-even
  return (u16)(r >> 16);
}

struct Params {
  const float* x;
  const u16* Bp2; const u16* Bp1; const u16* W1p;
  const float* Wih1t; const float* bs1; const float* bs2;
  const float* b1; const float* W2; const float* b2;
  u16* Acat; float* g1p; float* c1; float* c2; float* sb; float* pbuf;
  unsigned* bar;
  float* outs; float* stores;
};

// ---------------------------------------------------------------------------
// Contention-free grid barrier (multi-flag + generation broadcast).
// Arrival: each block release-stores its PRIVATE flag (128 B apart) -> no
// line ping-pong, fully parallel. Block 0's 256 threads acquire-poll one flag
// each, then thread 0 release-stores monotone `gen`; other blocks poll `gen`
// (read-only sharing). Visibility chain: release(flag_i) -> acquire(block0)
// -> release(gen) -> acquire(block_j). Grid is fully co-resident (256 blocks,
// 50KB LDS -> >=1 blk/CU at any VGPR count) so spinning cannot deadlock.
// ---------------------------------------------------------------------------
__device__ __forceinline__ void gbar(unsigned* flags, unsigned* gen, unsigned& lg) {
  const int tid = threadIdx.x, bid = blockIdx.x;
  const unsigned target = ++lg;
  __syncthreads();
  if (tid == 0)
    __hip_atomic_store(flags + bid * 32, target, __ATOMIC_RELEASE, __HIP_MEMORY_SCOPE_AGENT);
  if (bid == 0) {
    while (__hip_atomic_load(flags + tid * 32, __ATOMIC_ACQUIRE, __HIP_MEMORY_SCOPE_AGENT) < target)
      __builtin_amdgcn_s_sleep(1);
    __syncthreads();
    if (tid == 0)
      __hip_atomic_store(gen, target, __ATOMIC_RELEASE, __HIP_MEMORY_SCOPE_AGENT);
  } else {
    if (tid == 0)
      while (__hip_atomic_load(gen, __ATOMIC_ACQUIRE, __HIP_MEMORY_SCOPE_AGENT) < target)
        __builtin_amdgcn_s_sleep(2);
    __syncthreads();
  }
}

// ---------------------------------------------------------------------------
// One-time packing: weights -> bf16 MFMA fragment layout (round-1 verified).
// B fragment (kt, jt): lane l, elem e holds B[kt*32 + (l>>4)*8 + e][jt*16 + (l&15)].
// ---------------------------------------------------------------------------
__global__ void pack_kernel(const float* __restrict__ Wih1, const float* __restrict__ bih1,
                            const float* __restrict__ Whh1, const float* __restrict__ bhh1,
                            const float* __restrict__ Wih2, const float* __restrict__ bih2,
                            const float* __restrict__ Whh2, const float* __restrict__ bhh2,
                            const float* __restrict__ W1,
                            u16* __restrict__ Bp2, u16* __restrict__ Bp1, u16* __restrict__ W1p,
                            float* __restrict__ Wih1t, float* __restrict__ bs1, float* __restrict__ bs2) {
  const long NB2 = 48l * 192 * 512, NB1 = 24l * 192 * 512, NW1 = 24l * 32 * 512, NT = 9l * 3072;
  const long total = NB2 + NB1 + NW1 + NT + 3072 * 2;
  for (long idx = (long)blockIdx.x * 256 + threadIdx.x; idx < total; idx += (long)gridDim.x * 256) {
    if (idx < NB2) {                       // Wcat2 = [W_ih2 ; W_hh2] (K=1536)
      long kt = idx / (192 * 512); long r = idx % (192 * 512);
      int jt = (int)(r / 512); int s = (int)(r % 512);
      int ll = s >> 3, e = s & 7;
      int k = (int)kt * 32 + ((ll >> 4) * 8) + e;
      int j = jt * 16 + (ll & 15);
      float v = (k < 768) ? Wih2[j * 768 + k] : Whh2[j * 768 + k - 768];
      Bp2[idx] = f2bf(v);
    } else if (idx < NB2 + NB1) {          // W_hh1 (K=768)
      long i = idx - NB2;
      long kt = i / (192 * 512); long r = i % (192 * 512);
      int jt = (int)(r / 512); int s = (int)(r % 512);
      int ll = s >> 3, e = s & 7;
      int k = (int)kt * 32 + ((ll >> 4) * 8) + e;
      int j = jt * 16 + (ll & 15);
      Bp1[i] = f2bf(Whh1[j * 768 + k]);
    } else if (idx < NB2 + NB1 + NW1) {    // W1 (K=768, N=512)
      long i = idx - NB2 - NB1;
      long kt = i / (32 * 512); long r = i % (32 * 512);
      int jt = (int)(r / 512); int s = (int)(r % 512);
      int ll = s >> 3, e = s & 7;
      int k = (int)kt * 32 + ((ll >> 4) * 8) + e;
      int j = jt * 16 + (ll & 15);
      W1p[i] = f2bf(W1[j * 768 + k]);
    } else if (idx < NB2 + NB1 + NW1 + NT) {  // W_ih1 transposed (fp32)
      long i = idx - NB2 - NB1 - NW1;
      int k = (int)(i / 3072), j = (int)(i % 3072);
      Wih1t[i] = Wih1[j * 9 + k];
    } else {
      long i = idx - NB2 - NB1 - NW1 - NT;
      if (i < 3072) bs1[i] = bih1[i] + bhh1[i];
      else { long j = i - 3072; bs2[j] = bih2[j] + bhh2[j]; }
    }
  }
}

// ---------------------------------------------------------------------------
// phase H: out-reduction, exact fp32 store integration, h1(t+1) activation.
// 64 blocks x 4 rows. t == -1 bootstraps (no FC; x/bias terms added inline).
// ---------------------------------------------------------------------------
__device__ __forceinline__ void phase_H(const Params& P, int t, int tid, int bid,
                                        float (*xsb)[8]) {
  const int n0 = bid * 4;
  if (tid < 4) {
    int n = n0 + tid;
    float ov = 0.f;
    if (t >= 0) {
      const float* pb = P.pbuf + n * 8;
      ov = ((pb[0] + pb[1]) + (pb[2] + pb[3])) + ((pb[4] + pb[5]) + (pb[6] + pb[7])) + P.b2[0];
      P.outs[n * LSEQ + t] = ov;
    }
    if (t < 127) {
      float cs = P.sb[n] + P.x[(n * LSEQ + t + 1) * 8] - ov;   // exact fp32 integration
      P.sb[n] = cs;
      P.stores[n * LSEQ + t + 1] = cs;
      xsb[0][4 + tid] = cs;
    }
  }
  if (t == -1 && tid < 32)
    xsb[1 + (tid >> 3)][tid & 7] = P.x[((n0 + (tid >> 3)) * LSEQ) * 8 + (tid & 7)];
  __syncthreads();
  if (t >= 127) return;
  for (int p = tid; p < 3072; p += 256) {
    int r = p / 768, m = p - r * 768;
    int n = n0 + r;
    float cs = xsb[0][4 + r];
    float g[4];
#pragma unroll
    for (int q = 0; q < 4; ++q) {
      int j = m + q * 768;
      float base;
      if (t >= 0) base = P.g1p[n * 3072 + j];
      else {
        base = P.bs1[j];
#pragma unroll
        for (int k = 0; k < 8; ++k) base += xsb[1 + r][k] * P.Wih1t[k * 3072 + j];
      }
      g[q] = base + cs * P.Wih1t[8 * 3072 + j];
    }
    float co = P.c1[n * 768 + m];
    float cn = sigf(g[1]) * co + sigf(g[0]) * tanhfast(g[2]);
    float h = sigf(g[3]) * tanhfast(cn);
    P.c1[n * 768 + m] = cn;
    P.Acat[n * AROW + m] = f2bf(h);
  }
}

// ---------------------------------------------------------------------------
// Persistent kernel (plain launch, multi-flag grid barrier): 3 syncs/step.
//   phase A: gates2 GEMM+h2 act (blocks 0..191) || g1p GEMM+x fixup (192..255)
//   phase F: FC1+ReLU+W2 partials, 128 blocks (16 rows x 64 cols)
//   phase H: out/store/h1, 64 blocks x 4 rows
// Staging: triple-buffered global_load_lds, counted vmcnt(8) (depth-2).
// ---------------------------------------------------------------------------
__global__ __launch_bounds__(256) void lstm_fused(Params P) {
  __shared__ ushort8 sbuf[48 * 64];     // 48 KB: triple-buffered staging (3 x 16 frags)
  __shared__ float xsb[64][8];          // 2 KB: x rows (g1p fixup) / cs + bootstrap x (H)
  float (*fbuf)[64][16] = (float(*)[64][16])sbuf;  // 16 KB overlay, used post-K-loop only
  const int tid = threadIdx.x, l = tid & 63, w = tid >> 6;
  const int bid = blockIdx.x;
  unsigned* bgen = P.bar + 16;
  unsigned* bflags = P.bar + 32;
  unsigned lg = 0;

  if (bid < 64) phase_H(P, -1, tid, bid, xsb);
  gbar(bflags, bgen, lg);

  for (int t = 0; t < 128; ++t) {
    // ================= phase A =================
    if (bid < 192) {
      // ---- gates2: 64 rows x (4 quadrants x 16 cols), K=1536 ----
      const int mg = bid % 48, rowbase = (bid / 48) * 64;
      const int rdbase = 768 + (t & 1) * 768;        // h2(t-1)
      const int wrbase = 768 + ((t + 1) & 1) * 768;  // h2(t)
      auto stage_g2 = [&](int kc, int slot) {
#pragma unroll
        for (int i = 0; i < 4; ++i) {
          int f = w * 4 + i;                         // wave-uniform fragment id
          const u16* gp;
          if (f < 8) {                               // A: 4 row-tiles x 2 k-tiles
            int kt2 = f >> 2, rt = f & 3, kt = kc * 2 + kt2;
            int col = (kt >= 24) ? (rdbase + (kt - 24) * 32 + ((l >> 4) * 8))
                                 : (kt * 32 + ((l >> 4) * 8));
            gp = P.Acat + (rowbase + rt * 16 + (l & 15)) * AROW + col;
          } else {                                   // B: 4 quadrants x 2 k-tiles
            int g = f - 8, kt2 = g >> 2, q = g & 3, kt = kc * 2 + kt2;
            gp = P.Bp2 + (((long)(kt * 192 + q * 48 + mg)) << 9) + l * 8;
          }
          GLLDS(gp, &sbuf[(slot * 16 + f) * 64]);
        }
      };
      f32x4 acc[4] = {};
      stage_g2(0, 0);
      stage_g2(1, 1);
      for (int kc = 0; kc < 24; ++kc) {
        if (kc < 22) {
          stage_g2(kc + 2, (kc + 2) % 3);
          asm volatile("s_waitcnt vmcnt(8)" ::: "memory");
        } else if (kc == 22) {
          asm volatile("s_waitcnt vmcnt(4)" ::: "memory");
        } else {
          asm volatile("s_waitcnt vmcnt(0)" ::: "memory");
        }
        __builtin_amdgcn_s_barrier();
        __builtin_amdgcn_sched_barrier(0);
        const int base = (kc % 3) * 16;
#pragma unroll
        for (int kt2 = 0; kt2 < 2; ++kt2) {
          ushort8 bfr = sbuf[(base + 8 + kt2 * 4 + w) * 64 + l];
#pragma unroll
          for (int rt = 0; rt < 4; ++rt) {
            ushort8 a = sbuf[(base + kt2 * 4 + rt) * 64 + l];
            acc[rt] = MFMA_B16(a, bfr, acc[rt]);
          }
        }
        __builtin_amdgcn_sched_barrier(0);
        __builtin_amdgcn_s_barrier();
      }
      // epilogue: quadrant exchange -> h2/c2 update (fbuf overlays sbuf; all
      // MFMA reads of sbuf completed before the loop's final s_barrier)
#pragma unroll
      for (int rt = 0; rt < 4; ++rt)
#pragma unroll
        for (int reg = 0; reg < 4; ++reg) {
          int rl = rt * 16 + (l >> 4) * 4 + reg;
          fbuf[w][rl][l & 15] = acc[rt][reg] + P.bs2[w * 768 + mg * 16 + (l & 15)];
        }
      __syncthreads();
      for (int p = tid; p < 1024; p += 256) {
        int r = p >> 4, m = p & 15;
        float gi = fbuf[0][r][m], gf = fbuf[1][r][m], gg = fbuf[2][r][m], go = fbuf[3][r][m];
        int n = rowbase + r, mG = mg * 16 + m;
        float co = P.c2[n * 768 + mG];
        float cn = sigf(gf) * co + sigf(gi) * tanhfast(gg);
        float h = sigf(go) * tanhfast(cn);
        P.c2[n * 768 + mG] = cn;
        P.Acat[n * AROW + wrbase + mG] = f2bf(h);
      }
    } else {
      // ---- g1p: 64 rows x 192 cols, K=768; epilogue folds bias + x-projection ----
      const int b = bid - 192, rowbase = (b >> 4) * 64, jb = b & 15;
      if (t < 127) {
        for (int p = tid; p < 512; p += 256)
          xsb[p >> 3][p & 7] = P.x[((rowbase + (p >> 3)) * LSEQ + t + 1) * 8 + (p & 7)];
      } else {
        for (int p = tid; p < 512; p += 256) xsb[p >> 3][p & 7] = 0.f;
      }
      __syncthreads();
      auto stage_g1 = [&](int kt, int slot) {
#pragma unroll
        for (int i = 0; i < 4; ++i) {
          int f = w * 4 + i;
          const u16* gp;
          if (f < 4) {                               // A: 4 row-tiles (h1 cols)
            gp = P.Acat + (rowbase + f * 16 + (l & 15)) * AROW + kt * 32 + ((l >> 4) * 8);
          } else {                                   // B: 12 j-tiles
            int jt_l = f - 4;
            gp = P.Bp1 + (((long)(kt * 192 + jb * 12 + jt_l)) << 9) + l * 8;
          }
          GLLDS(gp, &sbuf[(slot * 16 + f) * 64]);
        }
      };
      f32x4 acc[3][4] = {};
      stage_g1(0, 0);
      stage_g1(1, 1);
      for (int kt = 0; kt < 24; ++kt) {
        if (kt < 22) {
          stage_g1(kt + 2, (kt + 2) % 3);
          asm volatile("s_waitcnt vmcnt(8)" ::: "memory");
        } else if (kt == 22) {
          asm volatile("s_waitcnt vmcnt(4)" ::: "memory");
        } else {
          asm volatile("s_waitcnt vmcnt(0)" ::: "memory");
        }
        __builtin_amdgcn_s_barrier();
        __builtin_amdgcn_sched_barrier(0);
        const int base = (kt % 3) * 16;
        ushort8 a_[4];
#pragma unroll
        for (int rt = 0; rt < 4; ++rt) a_[rt] = sbuf[(base + rt) * 64 + l];
#pragma unroll
        for (int jj = 0; jj < 3; ++jj) {
          ushort8 bfr = sbuf[(base + 4 + w * 3 + jj) * 64 + l];
#pragma unroll
          for (int rt = 0; rt < 4; ++rt)
            acc[jj][rt] = MFMA_B16(a_[rt], bfr, acc[jj][rt]);
        }
        __builtin_amdgcn_sched_barrier(0);
        __builtin_amdgcn_s_barrier();
      }
      // epilogue: g1p = acc + bs1 + x(t+1) . W_ih1[:,0:8]   (cs term added in phase H)
      float wc[3][8], bsv[3];
#pragma unroll
      for (int jj = 0; jj < 3; ++jj) {
        int col = (jb * 12 + w * 3 + jj) * 16 + (l & 15);
        bsv[jj] = P.bs1[col];
#pragma unroll
        for (int k = 0; k < 8; ++k) wc[jj][k] = P.Wih1t[k * 3072 + col];
      }
#pragma unroll
      for (int rt = 0; rt < 4; ++rt)
#pragma unroll
        for (int reg = 0; reg < 4; ++reg) {
          int rl = rt * 16 + (l >> 4) * 4 + reg;
          int n = rowbase + rl;
          float xv[8];
#pragma unroll
          for (int k = 0; k < 8; ++k) xv[k] = xsb[rl][k];
#pragma unroll
          for (int jj = 0; jj < 3; ++jj) {
            float v = acc[jj][rt][reg] + bsv[jj];
#pragma unroll
            for (int k = 0; k < 8; ++k) v += xv[k] * wc[jj][k];
            P.g1p[n * 3072 + (jb * 12 + w * 3 + jj) * 16 + (l & 15)] = v;
          }
        }
    }
    gbar(bflags, bgen, lg);

    // ========== phase F: FC partials (128 blocks: 16 rows x 64 cols) ==========
    if (bid < 128) {
      const int n0f = (bid >> 3) * 16, cg2 = bid & 7, ctg = cg2 * 4 + w;
      const int h2rd = 768 + ((t + 1) & 1) * 768;
      const u16* abase = P.Acat + (n0f + (l & 15)) * AROW + h2rd + ((l >> 4) * 8);
      const u16* bbase = P.W1p + ((long)ctg << 9) + l * 8;
      f32x4 facc = {};
#pragma unroll 6
      for (int kt = 0; kt < 24; ++kt) {
        ushort8 a = *reinterpret_cast<const ushort8*>(abase + kt * 32);
        ushort8 bf8 = *reinterpret_cast<const ushort8*>(bbase + kt * 16384);
        facc = MFMA_B16(a, bf8, facc);
      }
      int col = ctg * 16 + (l & 15);
      float w2v = P.W2[col], b1v = P.b1[col];
      float pr[4];
#pragma unroll
      for (int reg = 0; reg < 4; ++reg) pr[reg] = fmaxf(facc[reg] + b1v, 0.f) * w2v;
#pragma unroll
      for (int mm = 1; mm < 16; mm <<= 1)
#pragma unroll
        for (int reg = 0; reg < 4; ++reg) pr[reg] += __shfl_xor(pr[reg], mm);
      if ((l & 15) == 0)
#pragma unroll
        for (int reg = 0; reg < 4; ++reg) fbuf[w][(l >> 4) * 4 + reg][0] = pr[reg];
      __syncthreads();
      if (tid < 16)
        P.pbuf[(n0f + tid) * 8 + cg2] =
            fbuf[0][tid][0] + fbuf[1][tid][0] + fbuf[2][tid][0] + fbuf[3][tid][0];
    }
    gbar(bflags, bgen, lg);

    // ================= phase H =================
    if (bid < 64) phase_H(P, t, tid, bid, xsb);
    gbar(bflags, bgen, lg);
  }
}

extern "C" void kernel_launch(void* const* d_in, const int* in_sizes, int n_in,
                              void* d_out, int out_size, void* d_ws, size_t ws_size,
                              hipStream_t stream) {
  const float* x    = (const float*)d_in[0];
  const float* Wih1 = (const float*)d_in[1];
  const float* bih1 = (const float*)d_in[2];
  const float* Whh1 = (const float*)d_in[3];
  const float* bhh1 = (const float*)d_in[4];
  const float* Wih2 = (const float*)d_in[5];
  const float* bih2 = (const float*)d_in[6];
  const float* Whh2 = (const float*)d_in[7];
  const float* bhh2 = (const float*)d_in[8];
  const float* W1   = (const float*)d_in[9];
  const float* b1   = (const float*)d_in[10];
  const float* W2   = (const float*)d_in[11];
  const float* b2   = (const float*)d_in[12];

  char* ws = (char*)d_ws;
  u16* Bp2 = (u16*)(ws + OFF_BP2);
  u16* Bp1 = (u16*)(ws + OFF_BP1);
  u16* W1p = (u16*)(ws + OFF_W1P);
  float* Wih1t = (float*)(ws + OFF_WIH1T);
  float* bs1 = (float*)(ws + OFF_BS1);
  float* bs2 = (float*)(ws + OFF_BS2);
  float* g1p = (float*)(ws + OFF_G1P);
  float* pbuf = (float*)(ws + OFF_PBUF);
  u16* Acat = (u16*)(ws + OFF_ACAT);
  float* c1 = (float*)(ws + OFF_C1);
  float* c2 = (float*)(ws + OFF_C2);
  float* sb = (float*)(ws + OFF_SB);
  unsigned* bar = (unsigned*)(ws + OFF_BAR);
  float* outs = (float*)d_out;
  float* stores = outs + N_B * LSEQ;

  pack_kernel<<<2048, 256, 0, stream>>>(Wih1, bih1, Whh1, bhh1, Wih2, bih2, Whh2, bhh2, W1,
                                        Bp2, Bp1, W1p, Wih1t, bs1, bs2);
  hipMemsetAsync(ws + OFF_ZERO, 0, ZERO_BYTES, stream);

  Params Pr = {x, Bp2, Bp1, W1p, Wih1t, bs1, bs2, b1, W2, b2,
               Acat, g1p, c1, c2, sb, pbuf, bar, outs, stores};
  lstm_fused<<<NBLK, 256, 0, stream>>>(Pr);
}

// Round 5
// 7319.888 us; speedup vs baseline: 2.0480x; 1.9978x over previous
//
#include <hip/hip_runtime.h>

typedef unsigned short u16;
typedef __attribute__((ext_vector_type(8))) unsigned short ushort8;
typedef __attribute__((ext_vector_type(4))) float f32x4;
typedef __attribute__((ext_vector_type(8))) __bf16 bf16x8;

#define N_B 256
#define LSEQ 128
#define AROW 2304   // 768 (h1) + 2*768 (h2 double-buffer phases)
#define NBLK 256

#define MFMA_B16(a, b, c) __builtin_amdgcn_mfma_f32_16x16x32_bf16( \
    __builtin_bit_cast(bf16x8, a), __builtin_bit_cast(bf16x8, b), c, 0, 0, 0)

#define GLLDS(gp, lp) __builtin_amdgcn_global_load_lds( \
    (const __attribute__((address_space(1))) void*)(gp), \
    (__attribute__((address_space(3))) void*)(lp), 16, 0, 0)

// ---- workspace layout (byte offsets) ----
#define OFF_BP2   0ull
#define SZ_BP2    (48ull*192*512*2)
#define OFF_BP1   (OFF_BP2 + SZ_BP2)
#define SZ_BP1    (24ull*192*512*2)
#define OFF_W1P   (OFF_BP1 + SZ_BP1)
#define SZ_W1P    (24ull*32*512*2)
#define OFF_WIH1T (OFF_W1P + SZ_W1P)
#define SZ_WIH1T  (9ull*3072*4)
#define OFF_BS1   (OFF_WIH1T + SZ_WIH1T)
#define OFF_BS2   (OFF_BS1 + 3072*4)
#define OFF_G1P   (OFF_BS2 + 3072*4)
#define SZ_G1P    (256ull*3072*4)
#define OFF_PBUF  (OFF_G1P + SZ_G1P)
#define SZ_PBUF   (256ull*8*4)
#define OFF_ZERO  (OFF_PBUF + SZ_PBUF)
#define OFF_ACAT  OFF_ZERO
#define SZ_ACAT   (256ull*2304*2)
#define OFF_C1    (OFF_ACAT + SZ_ACAT)
#define OFF_C2    (OFF_C1 + 256ull*768*4)
#define OFF_SB    (OFF_C2 + 256ull*768*4)
#define OFF_BAR   (OFF_SB + 1024)      // bar[16]=gen; flags at bar+32 (256 x 32 uints)
#define SZ_BAR    (128 + 256*32*4)
#define OFF_END   (OFF_BAR + SZ_BAR)
#define ZERO_BYTES (OFF_END - OFF_ZERO)

__device__ __forceinline__ float sigf(float v) { return 1.f / (1.f + __expf(-v)); }
__device__ __forceinline__ float tanhfast(float v) { return 1.f - 2.f / (__expf(2.f * v) + 1.f); }
__device__ __forceinline__ u16 f2bf(float f) {
  union { float f; unsigned u; } v; v.f = f;
  unsigned r = v.u + 0x7fffu + ((v.u >> 16) & 1u);   // round-to-nearest-even
  return (u16)(r >> 16);
}

struct Params {
  const float* x;
  const u16* Bp2; const u16* Bp1; const u16* W1p;
  const float* Wih1t; const float* bs1; const float* bs2;
  const float* b1; const float* W2; const float* b2;
  u16* Acat; float* g1p; float* c1; float* c2; float* sb; float* pbuf;
  unsigned* bar;
  float* outs; float* stores;
};

// ---------------------------------------------------------------------------
// Grid barrier, invalidate-storm-free version.
// KEY CHANGE vs round 4: poll loops use RELAXED agent atomics. On gfx950 an
// agent-scope ACQUIRE load emits a full L1+L2 `buffer_inv` EVERY iteration;
// ~200 polling blocks at ~128-cycle period continuously invalidated every
// XCD's L2 while straggler blocks were still streaming their GEMM tiles --
// that was the 14.6 ms. Relaxed agent atomics compile to sc1-flagged loads
// (coherence-point reads: always fresh, no cache-wide side effects).
// Exactly ONE release (flag store -> one buffer_wbl2) and ONE acquire
// (post-poll gen load -> one buffer_inv) per block per barrier provide the
// cross-XCD visibility chain: release(flag_i) -> acquire(gen) happens-before
// all subsequent plain loads. Trailing __syncthreads orders the inv before
// the block's other waves issue phase loads. Grid (256 blocks, 50KB LDS) is
// fully co-resident at any VGPR count, so spinning cannot deadlock.
// ---------------------------------------------------------------------------
__device__ __forceinline__ void gbar(unsigned* flags, unsigned* gen, unsigned& lg) {
  const int tid = threadIdx.x, bid = blockIdx.x;
  const unsigned target = ++lg;
  __syncthreads();
  if (tid == 0)
    __hip_atomic_store(flags + bid * 32, target, __ATOMIC_RELEASE, __HIP_MEMORY_SCOPE_AGENT);
  if (bid == 0) {
    while (__hip_atomic_load(flags + tid * 32, __ATOMIC_RELAXED, __HIP_MEMORY_SCOPE_AGENT) < target)
      __builtin_amdgcn_s_sleep(1);
    __syncthreads();
    if (tid == 0)
      __hip_atomic_store(gen, target, __ATOMIC_RELEASE, __HIP_MEMORY_SCOPE_AGENT);
  } else {
    if (tid == 0)
      while (__hip_atomic_load(gen, __ATOMIC_RELAXED, __HIP_MEMORY_SCOPE_AGENT) < target)
        __builtin_amdgcn_s_sleep(2);
  }
  if (tid == 0)
    (void)__hip_atomic_load(gen, __ATOMIC_ACQUIRE, __HIP_MEMORY_SCOPE_AGENT);
  __syncthreads();
}

// ---------------------------------------------------------------------------
// One-time packing: weights -> bf16 MFMA fragment layout (round-1 verified).
// B fragment (kt, jt): lane l, elem e holds B[kt*32 + (l>>4)*8 + e][jt*16 + (l&15)].
// ---------------------------------------------------------------------------
__global__ void pack_kernel(const float* __restrict__ Wih1, const float* __restrict__ bih1,
                            const float* __restrict__ Whh1, const float* __restrict__ bhh1,
                            const float* __restrict__ Wih2, const float* __restrict__ bih2,
                            const float* __restrict__ Whh2, const float* __restrict__ bhh2,
                            const float* __restrict__ W1,
                            u16* __restrict__ Bp2, u16* __restrict__ Bp1, u16* __restrict__ W1p,
                            float* __restrict__ Wih1t, float* __restrict__ bs1, float* __restrict__ bs2) {
  const long NB2 = 48l * 192 * 512, NB1 = 24l * 192 * 512, NW1 = 24l * 32 * 512, NT = 9l * 3072;
  const long total = NB2 + NB1 + NW1 + NT + 3072 * 2;
  for (long idx = (long)blockIdx.x * 256 + threadIdx.x; idx < total; idx += (long)gridDim.x * 256) {
    if (idx < NB2) {                       // Wcat2 = [W_ih2 ; W_hh2] (K=1536)
      long kt = idx / (192 * 512); long r = idx % (192 * 512);
      int jt = (int)(r / 512); int s = (int)(r % 512);
      int ll = s >> 3, e = s & 7;
      int k = (int)kt * 32 + ((ll >> 4) * 8) + e;
      int j = jt * 16 + (ll & 15);
      float v = (k < 768) ? Wih2[j * 768 + k] : Whh2[j * 768 + k - 768];
      Bp2[idx] = f2bf(v);
    } else if (idx < NB2 + NB1) {          // W_hh1 (K=768)
      long i = idx - NB2;
      long kt = i / (192 * 512); long r = i % (192 * 512);
      int jt = (int)(r / 512); int s = (int)(r % 512);
      int ll = s >> 3, e = s & 7;
      int k = (int)kt * 32 + ((ll >> 4) * 8) + e;
      int j = jt * 16 + (ll & 15);
      Bp1[i] = f2bf(Whh1[j * 768 + k]);
    } else if (idx < NB2 + NB1 + NW1) {    // W1 (K=768, N=512)
      long i = idx - NB2 - NB1;
      long kt = i / (32 * 512); long r = i % (32 * 512);
      int jt = (int)(r / 512); int s = (int)(r % 512);
      int ll = s >> 3, e = s & 7;
      int k = (int)kt * 32 + ((ll >> 4) * 8) + e;
      int j = jt * 16 + (ll & 15);
      W1p[i] = f2bf(W1[j * 768 + k]);
    } else if (idx < NB2 + NB1 + NW1 + NT) {  // W_ih1 transposed (fp32)
      long i = idx - NB2 - NB1 - NW1;
      int k = (int)(i / 3072), j = (int)(i % 3072);
      Wih1t[i] = Wih1[j * 9 + k];
    } else {
      long i = idx - NB2 - NB1 - NW1 - NT;
      if (i < 3072) bs1[i] = bih1[i] + bhh1[i];
      else { long j = i - 3072; bs2[j] = bih2[j] + bhh2[j]; }
    }
  }
}

// ---------------------------------------------------------------------------
// phase H: out-reduction, exact fp32 store integration, h1(t+1) activation.
// 64 blocks x 4 rows. t == -1 bootstraps (no FC; x/bias terms added inline).
// ---------------------------------------------------------------------------
__device__ __forceinline__ void phase_H(const Params& P, int t, int tid, int bid,
                                        float (*xsb)[8]) {
  const int n0 = bid * 4;
  if (tid < 4) {
    int n = n0 + tid;
    float ov = 0.f;
    if (t >= 0) {
      const float* pb = P.pbuf + n * 8;
      ov = ((pb[0] + pb[1]) + (pb[2] + pb[3])) + ((pb[4] + pb[5]) + (pb[6] + pb[7])) + P.b2[0];
      P.outs[n * LSEQ + t] = ov;
    }
    if (t < 127) {
      float cs = P.sb[n] + P.x[(n * LSEQ + t + 1) * 8] - ov;   // exact fp32 integration
      P.sb[n] = cs;
      P.stores[n * LSEQ + t + 1] = cs;
      xsb[0][4 + tid] = cs;
    }
  }
  if (t == -1 && tid < 32)
    xsb[1 + (tid >> 3)][tid & 7] = P.x[((n0 + (tid >> 3)) * LSEQ) * 8 + (tid & 7)];
  __syncthreads();
  if (t >= 127) return;
  for (int p = tid; p < 3072; p += 256) {
    int r = p / 768, m = p - r * 768;
    int n = n0 + r;
    float cs = xsb[0][4 + r];
    float g[4];
#pragma unroll
    for (int q = 0; q < 4; ++q) {
      int j = m + q * 768;
      float base;
      if (t >= 0) base = P.g1p[n * 3072 + j];
      else {
        base = P.bs1[j];
#pragma unroll
        for (int k = 0; k < 8; ++k) base += xsb[1 + r][k] * P.Wih1t[k * 3072 + j];
      }
      g[q] = base + cs * P.Wih1t[8 * 3072 + j];
    }
    float co = P.c1[n * 768 + m];
    float cn = sigf(g[1]) * co + sigf(g[0]) * tanhfast(g[2]);
    float h = sigf(g[3]) * tanhfast(cn);
    P.c1[n * 768 + m] = cn;
    P.Acat[n * AROW + m] = f2bf(h);
  }
}

// ---------------------------------------------------------------------------
// Persistent kernel (plain launch, quiet-poll grid barrier): 3 syncs/step.
//   phase A: gates2 GEMM+h2 act (blocks 0..191) || g1p GEMM+x fixup (192..255)
//   phase F: FC1+ReLU+W2 partials, 128 blocks (16 rows x 64 cols)
//   phase H: out/store/h1, 64 blocks x 4 rows
// Staging: triple-buffered global_load_lds, counted vmcnt(8) (depth-2).
// ---------------------------------------------------------------------------
__global__ __launch_bounds__(256) void lstm_fused(Params P) {
  __shared__ ushort8 sbuf[48 * 64];     // 48 KB: triple-buffered staging (3 x 16 frags)
  __shared__ float xsb[64][8];          // 2 KB: x rows (g1p fixup) / cs + bootstrap x (H)
  float (*fbuf)[64][16] = (float(*)[64][16])sbuf;  // 16 KB overlay, used post-K-loop only
  const int tid = threadIdx.x, l = tid & 63, w = tid >> 6;
  const int bid = blockIdx.x;
  unsigned* bgen = P.bar + 16;
  unsigned* bflags = P.bar + 32;
  unsigned lg = 0;

  if (bid < 64) phase_H(P, -1, tid, bid, xsb);
  gbar(bflags, bgen, lg);

  for (int t = 0; t < 128; ++t) {
    // ================= phase A =================
    if (bid < 192) {
      // ---- gates2: 64 rows x (4 quadrants x 16 cols), K=1536 ----
      const int mg = bid % 48, rowbase = (bid / 48) * 64;
      const int rdbase = 768 + (t & 1) * 768;        // h2(t-1)
      const int wrbase = 768 + ((t + 1) & 1) * 768;  // h2(t)
      auto stage_g2 = [&](int kc, int slot) {
#pragma unroll
        for (int i = 0; i < 4; ++i) {
          int f = w * 4 + i;                         // wave-uniform fragment id
          const u16* gp;
          if (f < 8) {                               // A: 4 row-tiles x 2 k-tiles
            int kt2 = f >> 2, rt = f & 3, kt = kc * 2 + kt2;
            int col = (kt >= 24) ? (rdbase + (kt - 24) * 32 + ((l >> 4) * 8))
                                 : (kt * 32 + ((l >> 4) * 8));
            gp = P.Acat + (rowbase + rt * 16 + (l & 15)) * AROW + col;
          } else {                                   // B: 4 quadrants x 2 k-tiles
            int g = f - 8, kt2 = g >> 2, q = g & 3, kt = kc * 2 + kt2;
            gp = P.Bp2 + (((long)(kt * 192 + q * 48 + mg)) << 9) + l * 8;
          }
          GLLDS(gp, &sbuf[(slot * 16 + f) * 64]);
        }
      };
      f32x4 acc[4] = {};
      stage_g2(0, 0);
      stage_g2(1, 1);
      for (int kc = 0; kc < 24; ++kc) {
        if (kc < 22) {
          stage_g2(kc + 2, (kc + 2) % 3);
          asm volatile("s_waitcnt vmcnt(8)" ::: "memory");
        } else if (kc == 22) {
          asm volatile("s_waitcnt vmcnt(4)" ::: "memory");
        } else {
          asm volatile("s_waitcnt vmcnt(0)" ::: "memory");
        }
        __builtin_amdgcn_s_barrier();
        __builtin_amdgcn_sched_barrier(0);
        const int base = (kc % 3) * 16;
#pragma unroll
        for (int kt2 = 0; kt2 < 2; ++kt2) {
          ushort8 bfr = sbuf[(base + 8 + kt2 * 4 + w) * 64 + l];
#pragma unroll
          for (int rt = 0; rt < 4; ++rt) {
            ushort8 a = sbuf[(base + kt2 * 4 + rt) * 64 + l];
            acc[rt] = MFMA_B16(a, bfr, acc[rt]);
          }
        }
        __builtin_amdgcn_sched_barrier(0);
        __builtin_amdgcn_s_barrier();
      }
      // epilogue: quadrant exchange -> h2/c2 update (fbuf overlays sbuf; all
      // MFMA reads of sbuf completed before the loop's final s_barrier)
#pragma unroll
      for (int rt = 0; rt < 4; ++rt)
#pragma unroll
        for (int reg = 0; reg < 4; ++reg) {
          int rl = rt * 16 + (l >> 4) * 4 + reg;
          fbuf[w][rl][l & 15] = acc[rt][reg] + P.bs2[w * 768 + mg * 16 + (l & 15)];
        }
      __syncthreads();
      for (int p = tid; p < 1024; p += 256) {
        int r = p >> 4, m = p & 15;
        float gi = fbuf[0][r][m], gf = fbuf[1][r][m], gg = fbuf[2][r][m], go = fbuf[3][r][m];
        int n = rowbase + r, mG = mg * 16 + m;
        float co = P.c2[n * 768 + mG];
        float cn = sigf(gf) * co + sigf(gi) * tanhfast(gg);
        float h = sigf(go) * tanhfast(cn);
        P.c2[n * 768 + mG] = cn;
        P.Acat[n * AROW + wrbase + mG] = f2bf(h);
      }
    } else {
      // ---- g1p: 64 rows x 192 cols, K=768; epilogue folds bias + x-projection ----
      const int b = bid - 192, rowbase = (b >> 4) * 64, jb = b & 15;
      if (t < 127) {
        for (int p = tid; p < 512; p += 256)
          xsb[p >> 3][p & 7] = P.x[((rowbase + (p >> 3)) * LSEQ + t + 1) * 8 + (p & 7)];
      } else {
        for (int p = tid; p < 512; p += 256) xsb[p >> 3][p & 7] = 0.f;
      }
      __syncthreads();
      auto stage_g1 = [&](int kt, int slot) {
#pragma unroll
        for (int i = 0; i < 4; ++i) {
          int f = w * 4 + i;
          const u16* gp;
          if (f < 4) {                               // A: 4 row-tiles (h1 cols)
            gp = P.Acat + (rowbase + f * 16 + (l & 15)) * AROW + kt * 32 + ((l >> 4) * 8);
          } else {                                   // B: 12 j-tiles
            int jt_l = f - 4;
            gp = P.Bp1 + (((long)(kt * 192 + jb * 12 + jt_l)) << 9) + l * 8;
          }
          GLLDS(gp, &sbuf[(slot * 16 + f) * 64]);
        }
      };
      f32x4 acc[3][4] = {};
      stage_g1(0, 0);
      stage_g1(1, 1);
      for (int kt = 0; kt < 24; ++kt) {
        if (kt < 22) {
          stage_g1(kt + 2, (kt + 2) % 3);
          asm volatile("s_waitcnt vmcnt(8)" ::: "memory");
        } else if (kt == 22) {
          asm volatile("s_waitcnt vmcnt(4)" ::: "memory");
        } else {
          asm volatile("s_waitcnt vmcnt(0)" ::: "memory");
        }
        __builtin_amdgcn_s_barrier();
        __builtin_amdgcn_sched_barrier(0);
        const int base = (kt % 3) * 16;
        ushort8 a_[4];
#pragma unroll
        for (int rt = 0; rt < 4; ++rt) a_[rt] = sbuf[(base + rt) * 64 + l];
#pragma unroll
        for (int jj = 0; jj < 3; ++jj) {
          ushort8 bfr = sbuf[(base + 4 + w * 3 + jj) * 64 + l];
#pragma unroll
          for (int rt = 0; rt < 4; ++rt)
            acc[jj][rt] = MFMA_B16(a_[rt], bfr, acc[jj][rt]);
        }
        __builtin_amdgcn_sched_barrier(0);
        __builtin_amdgcn_s_barrier();
      }
      // epilogue: g1p = acc + bs1 + x(t+1) . W_ih1[:,0:8]   (cs term added in phase H)
      float wc[3][8], bsv[3];
#pragma unroll
      for (int jj = 0; jj < 3; ++jj) {
        int col = (jb * 12 + w * 3 + jj) * 16 + (l & 15);
        bsv[jj] = P.bs1[col];
#pragma unroll
        for (int k = 0; k < 8; ++k) wc[jj][k] = P.Wih1t[k * 3072 + col];
      }
#pragma unroll
      for (int rt = 0; rt < 4; ++rt)
#pragma unroll
        for (int reg = 0; reg < 4; ++reg) {
          int rl = rt * 16 + (l >> 4) * 4 + reg;
          int n = rowbase + rl;
          float xv[8];
#pragma unroll
          for (int k = 0; k < 8; ++k) xv[k] = xsb[rl][k];
#pragma unroll
          for (int jj = 0; jj < 3; ++jj) {
            float v = acc[jj][rt][reg] + bsv[jj];
#pragma unroll
            for (int k = 0; k < 8; ++k) v += xv[k] * wc[jj][k];
            P.g1p[n * 3072 + (jb * 12 + w * 3 + jj) * 16 + (l & 15)] = v;
          }
        }
    }
    gbar(bflags, bgen, lg);

    // ========== phase F: FC partials (128 blocks: 16 rows x 64 cols) ==========
    if (bid < 128) {
      const int n0f = (bid >> 3) * 16, cg2 = bid & 7, ctg = cg2 * 4 + w;
      const int h2rd = 768 + ((t + 1) & 1) * 768;
      const u16* abase = P.Acat + (n0f + (l & 15)) * AROW + h2rd + ((l >> 4) * 8);
      const u16* bbase = P.W1p + ((long)ctg << 9) + l * 8;
      f32x4 facc = {};
#pragma unroll 6
      for (int kt = 0; kt < 24; ++kt) {
        ushort8 a = *reinterpret_cast<const ushort8*>(abase + kt * 32);
        ushort8 bf8 = *reinterpret_cast<const ushort8*>(bbase + kt * 16384);
        facc = MFMA_B16(a, bf8, facc);
      }
      int col = ctg * 16 + (l & 15);
      float w2v = P.W2[col], b1v = P.b1[col];
      float pr[4];
#pragma unroll
      for (int reg = 0; reg < 4; ++reg) pr[reg] = fmaxf(facc[reg] + b1v, 0.f) * w2v;
#pragma unroll
      for (int mm = 1; mm < 16; mm <<= 1)
#pragma unroll
        for (int reg = 0; reg < 4; ++reg) pr[reg] += __shfl_xor(pr[reg], mm);
      if ((l & 15) == 0)
#pragma unroll
        for (int reg = 0; reg < 4; ++reg) fbuf[w][(l >> 4) * 4 + reg][0] = pr[reg];
      __syncthreads();
      if (tid < 16)
        P.pbuf[(n0f + tid) * 8 + cg2] =
            fbuf[0][tid][0] + fbuf[1][tid][0] + fbuf[2][tid][0] + fbuf[3][tid][0];
    }
    gbar(bflags, bgen, lg);

    // ================= phase H =================
    if (bid < 64) phase_H(P, t, tid, bid, xsb);
    gbar(bflags, bgen, lg);
  }
}

extern "C" void kernel_launch(void* const* d_in, const int* in_sizes, int n_in,
                              void* d_out, int out_size, void* d_ws, size_t ws_size,
                              hipStream_t stream) {
  const float* x    = (const float*)d_in[0];
  const float* Wih1 = (const float*)d_in[1];
  const float* bih1 = (const float*)d_in[2];
  const float* Whh1 = (const float*)d_in[3];
  const float* bhh1 = (const float*)d_in[4];
  const float* Wih2 = (const float*)d_in[5];
  const float* bih2 = (const float*)d_in[6];
  const float* Whh2 = (const float*)d_in[7];
  const float* bhh2 = (const float*)d_in[8];
  const float* W1   = (const float*)d_in[9];
  const float* b1   = (const float*)d_in[10];
  const float* W2   = (const float*)d_in[11];
  const float* b2   = (const float*)d_in[12];

  char* ws = (char*)d_ws;
  u16* Bp2 = (u16*)(ws + OFF_BP2);
  u16* Bp1 = (u16*)(ws + OFF_BP1);
  u16* W1p = (u16*)(ws + OFF_W1P);
  float* Wih1t = (float*)(ws + OFF_WIH1T);
  float* bs1 = (float*)(ws + OFF_BS1);
  float* bs2 = (float*)(ws + OFF_BS2);
  float* g1p = (float*)(ws + OFF_G1P);
  float* pbuf = (float*)(ws + OFF_PBUF);
  u16* Acat = (u16*)(ws + OFF_ACAT);
  float* c1 = (float*)(ws + OFF_C1);
  float* c2 = (float*)(ws + OFF_C2);
  float* sb = (float*)(ws + OFF_SB);
  unsigned* bar = (unsigned*)(ws + OFF_BAR);
  float* outs = (float*)d_out;
  float* stores = outs + N_B * LSEQ;

  pack_kernel<<<2048, 256, 0, stream>>>(Wih1, bih1, Whh1, bhh1, Wih2, bih2, Whh2, bhh2, W1,
                                        Bp2, Bp1, W1p, Wih1t, bs1, bs2);
  hipMemsetAsync(ws + OFF_ZERO, 0, ZERO_BYTES, stream);

  Params Pr = {x, Bp2, Bp1, W1p, Wih1t, bs1, bs2, b1, W2, b2,
               Acat, g1p, c1, c2, sb, pbuf, bar, outs, stores};
  lstm_fused<<<NBLK, 256, 0, stream>>>(Pr);
}

// Round 6
// 4714.459 us; speedup vs baseline: 3.1798x; 1.5526x over previous
//
#include <hip/hip_runtime.h>

typedef unsigned short u16;
typedef __attribute__((ext_vector_type(8))) unsigned short ushort8;
typedef __attribute__((ext_vector_type(4))) float f32x4;
typedef __attribute__((ext_vector_type(8))) __bf16 bf16x8;

#define N_B 256
#define LSEQ 128
#define AROW 2304   // 768 (h1) + 2*768 (h2 double-buffer phases)
#define NBLK 256

#define MFMA_B16(a, b, c) __builtin_amdgcn_mfma_f32_16x16x32_bf16( \
    __builtin_bit_cast(bf16x8, a), __builtin_bit_cast(bf16x8, b), c, 0, 0, 0)

// plain cached staging (read-only weights)
#define GLLDS(gp, lp) __builtin_amdgcn_global_load_lds( \
    (const __attribute__((address_space(1))) void*)(gp), \
    (__attribute__((address_space(3))) void*)(lp), 16, 0, 0)
// coherent staging (mutable cross-block data): aux=17 = sc0|sc1 -> reads
// through to the MALL coherence point, never served from (or allocated
// into) possibly-stale L1/L2.
#define GLLDS_C(gp, lp) __builtin_amdgcn_global_load_lds( \
    (const __attribute__((address_space(1))) void*)(gp), \
    (__attribute__((address_space(3))) void*)(lp), 16, 0, 17)

#define ATOMIC_LD(p) __hip_atomic_load((p), __ATOMIC_RELAXED, __HIP_MEMORY_SCOPE_AGENT)
#define ATOMIC_ST(p, v) __hip_atomic_store((p), (v), __ATOMIC_RELAXED, __HIP_MEMORY_SCOPE_AGENT)

// ---- workspace layout (byte offsets) ----
#define OFF_BP2   0ull
#define SZ_BP2    (48ull*192*512*2)
#define OFF_BP1   (OFF_BP2 + SZ_BP2)
#define SZ_BP1    (24ull*192*512*2)
#define OFF_W1P   (OFF_BP1 + SZ_BP1)
#define SZ_W1P    (24ull*32*512*2)
#define OFF_WIH1T (OFF_W1P + SZ_W1P)
#define SZ_WIH1T  (9ull*3072*4)
#define OFF_BS1   (OFF_WIH1T + SZ_WIH1T)
#define OFF_BS2   (OFF_BS1 + 3072*4)
#define OFF_G1P   (OFF_BS2 + 3072*4)
#define SZ_G1P    (256ull*3072*4)
#define OFF_PBUF  (OFF_G1P + SZ_G1P)
#define SZ_PBUF   (256ull*8*4)
#define OFF_ZERO  (OFF_PBUF + SZ_PBUF)
#define OFF_ACAT  OFF_ZERO
#define SZ_ACAT   (256ull*2304*2)
#define OFF_C1    (OFF_ACAT + SZ_ACAT)
#define OFF_C2    (OFF_C1 + 256ull*768*4)
#define OFF_SB    (OFF_C2 + 256ull*768*4)
#define OFF_BAR   (OFF_SB + 1024)      // bar[16]=gen; flags at bar+32 (256 x 32 uints)
#define SZ_BAR    (128 + 256*32*4)
#define OFF_END   (OFF_BAR + SZ_BAR)
#define ZERO_BYTES (OFF_END - OFF_ZERO)

__device__ __forceinline__ float sigf(float v) { return 1.f / (1.f + __expf(-v)); }
__device__ __forceinline__ float tanhfast(float v) { return 1.f - 2.f / (__expf(2.f * v) + 1.f); }
__device__ __forceinline__ u16 f2bf(float f) {
  union { float f; unsigned u; } v; v.f = f;
  unsigned r = v.u + 0x7fffu + ((v.u >> 16) & 1u);   // round-to-nearest-even
  return (u16)(r >> 16);
}

struct Params {
  const float* x;
  const u16* Bp2; const u16* Bp1; const u16* W1p;
  const float* Wih1t; const float* bs1; const float* bs2;
  const float* b1; const float* W2; const float* b2;
  u16* Acat; float* g1p; float* c1; float* c2; float* sb; float* pbuf;
  unsigned* bar;
  float* outs; float* stores;
};

// ---------------------------------------------------------------------------
// Grid barrier with ZERO cache maintenance (the round-6 causal change).
// Round 5 kept one acquire (buffer_inv = full L1+L2 invalidate) per block per
// barrier: 385 barriers evicted the L2-resident weights every phase -> 11.5
// MB/step HBM re-stream at 206 GB/s = the whole runtime. Now ALL cross-block
// data moves via sc1-flagged accesses (relaxed agent atomics / GLLDS aux=17)
// that are coherent at the MALL by construction, so the barrier needs no
// inv/wbl2 at all. Ordering: every wave drains vmcnt(0) (its coherent stores
// reached the coherence point) before the flag store; readers sit behind the
// data-dependent poll + __syncthreads. Weights/private state stay plain-
// cached in L2 across all 128 steps. Grid (256 blocks, 50KB LDS) is fully
// co-resident at any VGPR count, so spinning cannot deadlock.
// ---------------------------------------------------------------------------
__device__ __forceinline__ void gbar(unsigned* flags, unsigned* gen, unsigned& lg) {
  const int tid = threadIdx.x, bid = blockIdx.x;
  const unsigned target = ++lg;
  asm volatile("s_waitcnt vmcnt(0)" ::: "memory");   // per-wave store drain
  __syncthreads();
  if (tid == 0)
    ATOMIC_ST(flags + bid * 32, target);
  if (bid == 0) {
    while (ATOMIC_LD(flags + tid * 32) < target) __builtin_amdgcn_s_sleep(1);
    __syncthreads();
    if (tid == 0) ATOMIC_ST(gen, target);
  } else {
    if (tid == 0)
      while (ATOMIC_LD(gen) < target) __builtin_amdgcn_s_sleep(2);
  }
  __syncthreads();
}

// ---------------------------------------------------------------------------
// One-time packing: weights -> bf16 MFMA fragment layout (round-1 verified).
// B fragment (kt, jt): lane l, elem e holds B[kt*32 + (l>>4)*8 + e][jt*16 + (l&15)].
// ---------------------------------------------------------------------------
__global__ void pack_kernel(const float* __restrict__ Wih1, const float* __restrict__ bih1,
                            const float* __restrict__ Whh1, const float* __restrict__ bhh1,
                            const float* __restrict__ Wih2, const float* __restrict__ bih2,
                            const float* __restrict__ Whh2, const float* __restrict__ bhh2,
                            const float* __restrict__ W1,
                            u16* __restrict__ Bp2, u16* __restrict__ Bp1, u16* __restrict__ W1p,
                            float* __restrict__ Wih1t, float* __restrict__ bs1, float* __restrict__ bs2) {
  const long NB2 = 48l * 192 * 512, NB1 = 24l * 192 * 512, NW1 = 24l * 32 * 512, NT = 9l * 3072;
  const long total = NB2 + NB1 + NW1 + NT + 3072 * 2;
  for (long idx = (long)blockIdx.x * 256 + threadIdx.x; idx < total; idx += (long)gridDim.x * 256) {
    if (idx < NB2) {                       // Wcat2 = [W_ih2 ; W_hh2] (K=1536)
      long kt = idx / (192 * 512); long r = idx % (192 * 512);
      int jt = (int)(r / 512); int s = (int)(r % 512);
      int ll = s >> 3, e = s & 7;
      int k = (int)kt * 32 + ((ll >> 4) * 8) + e;
      int j = jt * 16 + (ll & 15);
      float v = (k < 768) ? Wih2[j * 768 + k] : Whh2[j * 768 + k - 768];
      Bp2[idx] = f2bf(v);
    } else if (idx < NB2 + NB1) {          // W_hh1 (K=768)
      long i = idx - NB2;
      long kt = i / (192 * 512); long r = i % (192 * 512);
      int jt = (int)(r / 512); int s = (int)(r % 512);
      int ll = s >> 3, e = s & 7;
      int k = (int)kt * 32 + ((ll >> 4) * 8) + e;
      int j = jt * 16 + (ll & 15);
      Bp1[i] = f2bf(Whh1[j * 768 + k]);
    } else if (idx < NB2 + NB1 + NW1) {    // W1 (K=768, N=512)
      long i = idx - NB2 - NB1;
      long kt = i / (32 * 512); long r = i % (32 * 512);
      int jt = (int)(r / 512); int s = (int)(r % 512);
      int ll = s >> 3, e = s & 7;
      int k = (int)kt * 32 + ((ll >> 4) * 8) + e;
      int j = jt * 16 + (ll & 15);
      W1p[i] = f2bf(W1[j * 768 + k]);
    } else if (idx < NB2 + NB1 + NW1 + NT) {  // W_ih1 transposed (fp32)
      long i = idx - NB2 - NB1 - NW1;
      int k = (int)(i / 3072), j = (int)(i % 3072);
      Wih1t[i] = Wih1[j * 9 + k];
    } else {
      long i = idx - NB2 - NB1 - NW1 - NT;
      if (i < 3072) bs1[i] = bih1[i] + bhh1[i];
      else { long j = i - 3072; bs2[j] = bih2[j] + bhh2[j]; }
    }
  }
}

// ---------------------------------------------------------------------------
// phase H: out-reduction, exact fp32 store integration, h1(t+1) activation.
// 64 blocks x 4 rows. t == -1 bootstraps. Mutable cross-block data (pbuf,
// g1p reads; Acat h1 writes) via relaxed agent atomics; c1/sb private-cached.
// ---------------------------------------------------------------------------
__device__ __forceinline__ void phase_H(const Params& P, int t, int tid, int bid,
                                        float (*xsb)[8]) {
  const int n0 = bid * 4;
  if (tid < 4) {
    int n = n0 + tid;
    float ov = 0.f;
    if (t >= 0) {
      float pb[8];
#pragma unroll
      for (int i = 0; i < 8; ++i) pb[i] = ATOMIC_LD(P.pbuf + n * 8 + i);
      ov = ((pb[0] + pb[1]) + (pb[2] + pb[3])) + ((pb[4] + pb[5]) + (pb[6] + pb[7])) + P.b2[0];
      P.outs[n * LSEQ + t] = ov;
    }
    if (t < 127) {
      float cs = P.sb[n] + P.x[(n * LSEQ + t + 1) * 8] - ov;   // exact fp32 integration
      P.sb[n] = cs;
      P.stores[n * LSEQ + t + 1] = cs;
      xsb[0][4 + tid] = cs;
    }
  }
  if (t == -1 && tid < 32)
    xsb[1 + (tid >> 3)][tid & 7] = P.x[((n0 + (tid >> 3)) * LSEQ) * 8 + (tid & 7)];
  __syncthreads();
  if (t >= 127) return;
  for (int p = tid; p < 1536; p += 256) {            // 4 rows x 384 col-pairs
    int r = p / 384, mp = (p - r * 384) * 2;
    int n = n0 + r;
    float cs = xsb[0][4 + r];
    float ga[4], gb[4];
#pragma unroll
    for (int q = 0; q < 4; ++q) {
      int j = mp + q * 768;
      float b0, b1;
      if (t >= 0) {
        union { unsigned long long u; float f[2]; } cv;
        cv.u = ATOMIC_LD((const unsigned long long*)(P.g1p + n * 3072 + j));
        b0 = cv.f[0]; b1 = cv.f[1];
      } else {
        b0 = P.bs1[j]; b1 = P.bs1[j + 1];
#pragma unroll
        for (int k = 0; k < 8; ++k) {
          b0 += xsb[1 + r][k] * P.Wih1t[k * 3072 + j];
          b1 += xsb[1 + r][k] * P.Wih1t[k * 3072 + j + 1];
        }
      }
      ga[q] = b0 + cs * P.Wih1t[8 * 3072 + j];
      gb[q] = b1 + cs * P.Wih1t[8 * 3072 + j + 1];
    }
    float co0 = P.c1[n * 768 + mp], co1 = P.c1[n * 768 + mp + 1];
    float cn0 = sigf(ga[1]) * co0 + sigf(ga[0]) * tanhfast(ga[2]);
    float cn1 = sigf(gb[1]) * co1 + sigf(gb[0]) * tanhfast(gb[2]);
    float h0 = sigf(ga[3]) * tanhfast(cn0);
    float h1 = sigf(gb[3]) * tanhfast(cn1);
    P.c1[n * 768 + mp] = cn0;
    P.c1[n * 768 + mp + 1] = cn1;
    unsigned pk = (unsigned)f2bf(h0) | ((unsigned)f2bf(h1) << 16);
    ATOMIC_ST((unsigned*)(P.Acat + n * AROW + mp), pk);
  }
}

// ---------------------------------------------------------------------------
// Persistent kernel: 3 grid syncs/step, no cache-wide maintenance anywhere.
//   phase A: gates2 GEMM+h2 act (blocks 0..191) || g1p GEMM+x fixup (192..255)
//   phase F: FC1+ReLU+W2 partials, 128 blocks (A staged coherently into LDS)
//   phase H: out/store/h1, 64 blocks x 4 rows
// ---------------------------------------------------------------------------
__global__ __launch_bounds__(256) void lstm_fused(Params P) {
  __shared__ ushort8 sbuf[48 * 64];     // 48 KB: triple-buffered staging (3 x 16 frags)
  __shared__ float xsb[64][8];          // 2 KB
  float (*fbuf)[64][16] = (float(*)[64][16])sbuf;  // 16 KB overlay (bytes 0..16K)
  const int tid = threadIdx.x, l = tid & 63, w = tid >> 6;
  const int bid = blockIdx.x;
  unsigned* bgen = P.bar + 16;
  unsigned* bflags = P.bar + 32;
  unsigned lg = 0;

  if (bid < 64) phase_H(P, -1, tid, bid, xsb);
  gbar(bflags, bgen, lg);

  for (int t = 0; t < 128; ++t) {
    // ================= phase A =================
    if (bid < 192) {
      // ---- gates2: 64 rows x (4 quadrants x 16 cols), K=1536 ----
      const int mg = bid % 48, rowbase = (bid / 48) * 64;
      const int rdbase = 768 + (t & 1) * 768;        // h2(t-1)
      const int wrbase = 768 + ((t + 1) & 1) * 768;  // h2(t)
      auto stage_g2 = [&](int kc, int slot) {
#pragma unroll
        for (int i = 0; i < 4; ++i) {
          int f = w * 4 + i;                         // wave-uniform fragment id
          if (f < 8) {                               // A (mutable): coherent
            int kt2 = f >> 2, rt = f & 3, kt = kc * 2 + kt2;
            int col = (kt >= 24) ? (rdbase + (kt - 24) * 32 + ((l >> 4) * 8))
                                 : (kt * 32 + ((l >> 4) * 8));
            const u16* gp = P.Acat + (rowbase + rt * 16 + (l & 15)) * AROW + col;
            GLLDS_C(gp, &sbuf[(slot * 16 + f) * 64]);
          } else {                                   // B (weights): plain cached
            int g = f - 8, kt2 = g >> 2, q = g & 3, kt = kc * 2 + kt2;
            const u16* gp = P.Bp2 + (((long)(kt * 192 + q * 48 + mg)) << 9) + l * 8;
            GLLDS(gp, &sbuf[(slot * 16 + f) * 64]);
          }
        }
      };
      f32x4 acc[4] = {};
      stage_g2(0, 0);
      stage_g2(1, 1);
      for (int kc = 0; kc < 24; ++kc) {
        if (kc < 22) {
          stage_g2(kc + 2, (kc + 2) % 3);
          asm volatile("s_waitcnt vmcnt(8)" ::: "memory");
        } else if (kc == 22) {
          asm volatile("s_waitcnt vmcnt(4)" ::: "memory");
        } else {
          asm volatile("s_waitcnt vmcnt(0)" ::: "memory");
        }
        __builtin_amdgcn_s_barrier();
        __builtin_amdgcn_sched_barrier(0);
        const int base = (kc % 3) * 16;
#pragma unroll
        for (int kt2 = 0; kt2 < 2; ++kt2) {
          ushort8 bfr = sbuf[(base + 8 + kt2 * 4 + w) * 64 + l];
#pragma unroll
          for (int rt = 0; rt < 4; ++rt) {
            ushort8 a = sbuf[(base + kt2 * 4 + rt) * 64 + l];
            acc[rt] = MFMA_B16(a, bfr, acc[rt]);
          }
        }
        __builtin_amdgcn_sched_barrier(0);
        __builtin_amdgcn_s_barrier();
      }
      // epilogue: quadrant exchange -> h2/c2 update (paired coherent h2 store)
#pragma unroll
      for (int rt = 0; rt < 4; ++rt)
#pragma unroll
        for (int reg = 0; reg < 4; ++reg) {
          int rl = rt * 16 + (l >> 4) * 4 + reg;
          fbuf[w][rl][l & 15] = acc[rt][reg] + P.bs2[w * 768 + mg * 16 + (l & 15)];
        }
      __syncthreads();
      for (int p = tid; p < 512; p += 256) {         // 64 rows x 8 col-pairs
        int r = p >> 3, pp = (p & 7) * 2;
        int n = rowbase + r, mG = mg * 16 + pp;
        float gi0 = fbuf[0][r][pp], gi1 = fbuf[0][r][pp + 1];
        float gf0 = fbuf[1][r][pp], gf1 = fbuf[1][r][pp + 1];
        float gg0 = fbuf[2][r][pp], gg1 = fbuf[2][r][pp + 1];
        float go0 = fbuf[3][r][pp], go1 = fbuf[3][r][pp + 1];
        float co0 = P.c2[n * 768 + mG], co1 = P.c2[n * 768 + mG + 1];
        float cn0 = sigf(gf0) * co0 + sigf(gi0) * tanhfast(gg0);
        float cn1 = sigf(gf1) * co1 + sigf(gi1) * tanhfast(gg1);
        float h0 = sigf(go0) * tanhfast(cn0);
        float h1 = sigf(go1) * tanhfast(cn1);
        P.c2[n * 768 + mG] = cn0;
        P.c2[n * 768 + mG + 1] = cn1;
        unsigned pk = (unsigned)f2bf(h0) | ((unsigned)f2bf(h1) << 16);
        ATOMIC_ST((unsigned*)(P.Acat + n * AROW + wrbase + mG), pk);
      }
    } else {
      // ---- g1p: 64 rows x 192 cols, K=768; epilogue folds bias + x-projection ----
      const int b = bid - 192, rowbase = (b >> 4) * 64, jb = b & 15;
      if (t < 127) {
        for (int p = tid; p < 512; p += 256)
          xsb[p >> 3][p & 7] = P.x[((rowbase + (p >> 3)) * LSEQ + t + 1) * 8 + (p & 7)];
      } else {
        for (int p = tid; p < 512; p += 256) xsb[p >> 3][p & 7] = 0.f;
      }
      __syncthreads();
      auto stage_g1 = [&](int kt, int slot) {
#pragma unroll
        for (int i = 0; i < 4; ++i) {
          int f = w * 4 + i;
          if (f < 4) {                               // A (mutable h1): coherent
            const u16* gp = P.Acat + (rowbase + f * 16 + (l & 15)) * AROW + kt * 32 + ((l >> 4) * 8);
            GLLDS_C(gp, &sbuf[(slot * 16 + f) * 64]);
          } else {                                   // B (weights): plain cached
            int jt_l = f - 4;
            const u16* gp = P.Bp1 + (((long)(kt * 192 + jb * 12 + jt_l)) << 9) + l * 8;
            GLLDS(gp, &sbuf[(slot * 16 + f) * 64]);
          }
        }
      };
      f32x4 acc[3][4] = {};
      stage_g1(0, 0);
      stage_g1(1, 1);
      for (int kt = 0; kt < 24; ++kt) {
        if (kt < 22) {
          stage_g1(kt + 2, (kt + 2) % 3);
          asm volatile("s_waitcnt vmcnt(8)" ::: "memory");
        } else if (kt == 22) {
          asm volatile("s_waitcnt vmcnt(4)" ::: "memory");
        } else {
          asm volatile("s_waitcnt vmcnt(0)" ::: "memory");
        }
        __builtin_amdgcn_s_barrier();
        __builtin_amdgcn_sched_barrier(0);
        const int base = (kt % 3) * 16;
        ushort8 a_[4];
#pragma unroll
        for (int rt = 0; rt < 4; ++rt) a_[rt] = sbuf[(base + rt) * 64 + l];
#pragma unroll
        for (int jj = 0; jj < 3; ++jj) {
          ushort8 bfr = sbuf[(base + 4 + w * 3 + jj) * 64 + l];
#pragma unroll
          for (int rt = 0; rt < 4; ++rt)
            acc[jj][rt] = MFMA_B16(a_[rt], bfr, acc[jj][rt]);
        }
        __builtin_amdgcn_sched_barrier(0);
        __builtin_amdgcn_s_barrier();
      }
      // epilogue: g1p = acc + bs1 + x(t+1) . W_ih1[:,0:8]  (coherent stores)
      float wc[3][8], bsv[3];
#pragma unroll
      for (int jj = 0; jj < 3; ++jj) {
        int col = (jb * 12 + w * 3 + jj) * 16 + (l & 15);
        bsv[jj] = P.bs1[col];
#pragma unroll
        for (int k = 0; k < 8; ++k) wc[jj][k] = P.Wih1t[k * 3072 + col];
      }
#pragma unroll
      for (int rt = 0; rt < 4; ++rt)
#pragma unroll
        for (int reg = 0; reg < 4; ++reg) {
          int rl = rt * 16 + (l >> 4) * 4 + reg;
          int n = rowbase + rl;
          float xv[8];
#pragma unroll
          for (int k = 0; k < 8; ++k) xv[k] = xsb[rl][k];
#pragma unroll
          for (int jj = 0; jj < 3; ++jj) {
            float v = acc[jj][rt][reg] + bsv[jj];
#pragma unroll
            for (int k = 0; k < 8; ++k) v += xv[k] * wc[jj][k];
            ATOMIC_ST(P.g1p + n * 3072 + (jb * 12 + w * 3 + jj) * 16 + (l & 15), v);
          }
        }
    }
    gbar(bflags, bgen, lg);

    // ========== phase F: FC partials (128 blocks: 16 rows x 64 cols) ==========
    if (bid < 128) {
      ushort8* fst = sbuf + 1024;        // 24 KB A-stage (bytes 16K..40K, clear of fbuf)
      const int n0f = (bid >> 3) * 16, cg2 = bid & 7, ctg = cg2 * 4 + w;
      const int h2rd = 768 + ((t + 1) & 1) * 768;
#pragma unroll
      for (int i = 0; i < 6; ++i) {      // coherent-stage h2 rows: slot c*64+l = [colblk][row]
        int c = w * 6 + i;
        const u16* gp = P.Acat + (n0f + (l & 15)) * AROW + h2rd + c * 32 + ((l >> 4) * 8);
        GLLDS_C(gp, &fst[c * 64]);
      }
      asm volatile("s_waitcnt vmcnt(0)" ::: "memory");
      __syncthreads();
      const u16* bbase = P.W1p + ((long)ctg << 9) + l * 8;
      f32x4 facc = {};
#pragma unroll 6
      for (int kt = 0; kt < 24; ++kt) {
        ushort8 a = fst[kt * 64 + l];    // conflict-free: wave reads contiguous 1KB
        ushort8 bf8 = *reinterpret_cast<const ushort8*>(bbase + kt * 16384);
        facc = MFMA_B16(a, bf8, facc);
      }
      int col = ctg * 16 + (l & 15);
      float w2v = P.W2[col], b1v = P.b1[col];
      float pr[4];
#pragma unroll
      for (int reg = 0; reg < 4; ++reg) pr[reg] = fmaxf(facc[reg] + b1v, 0.f) * w2v;
#pragma unroll
      for (int mm = 1; mm < 16; mm <<= 1)
#pragma unroll
        for (int reg = 0; reg < 4; ++reg) pr[reg] += __shfl_xor(pr[reg], mm);
      if ((l & 15) == 0)
#pragma unroll
        for (int reg = 0; reg < 4; ++reg) fbuf[w][(l >> 4) * 4 + reg][0] = pr[reg];
      __syncthreads();
      if (tid < 16)
        ATOMIC_ST(P.pbuf + (n0f + tid) * 8 + cg2,
                  fbuf[0][tid][0] + fbuf[1][tid][0] + fbuf[2][tid][0] + fbuf[3][tid][0]);
    }
    gbar(bflags, bgen, lg);

    // ================= phase H =================
    if (bid < 64) phase_H(P, t, tid, bid, xsb);
    gbar(bflags, bgen, lg);
  }
}

extern "C" void kernel_launch(void* const* d_in, const int* in_sizes, int n_in,
                              void* d_out, int out_size, void* d_ws, size_t ws_size,
                              hipStream_t stream) {
  const float* x    = (const float*)d_in[0];
  const float* Wih1 = (const float*)d_in[1];
  const float* bih1 = (const float*)d_in[2];
  const float* Whh1 = (const float*)d_in[3];
  const float* bhh1 = (const float*)d_in[4];
  const float* Wih2 = (const float*)d_in[5];
  const float* bih2 = (const float*)d_in[6];
  const float* Whh2 = (const float*)d_in[7];
  const float* bhh2 = (const float*)d_in[8];
  const float* W1   = (const float*)d_in[9];
  const float* b1   = (const float*)d_in[10];
  const float* W2   = (const float*)d_in[11];
  const float* b2   = (const float*)d_in[12];

  char* ws = (char*)d_ws;
  u16* Bp2 = (u16*)(ws + OFF_BP2);
  u16* Bp1 = (u16*)(ws + OFF_BP1);
  u16* W1p = (u16*)(ws + OFF_W1P);
  float* Wih1t = (float*)(ws + OFF_WIH1T);
  float* bs1 = (float*)(ws + OFF_BS1);
  float* bs2 = (float*)(ws + OFF_BS2);
  float* g1p = (float*)(ws + OFF_G1P);
  float* pbuf = (float*)(ws + OFF_PBUF);
  u16* Acat = (u16*)(ws + OFF_ACAT);
  float* c1 = (float*)(ws + OFF_C1);
  float* c2 = (float*)(ws + OFF_C2);
  float* sb = (float*)(ws + OFF_SB);
  unsigned* bar = (unsigned*)(ws + OFF_BAR);
  float* outs = (float*)d_out;
  float* stores = outs + N_B * LSEQ;

  pack_kernel<<<2048, 256, 0, stream>>>(Wih1, bih1, Whh1, bhh1, Wih2, bih2, Whh2, bhh2, W1,
                                        Bp2, Bp1, W1p, Wih1t, bs1, bs2);
  hipMemsetAsync(ws + OFF_ZERO, 0, ZERO_BYTES, stream);

  Params Pr = {x, Bp2, Bp1, W1p, Wih1t, bs1, bs2, b1, W2, b2,
               Acat, g1p, c1, c2, sb, pbuf, bar, outs, stores};
  lstm_fused<<<NBLK, 256, 0, stream>>>(Pr);
}